// Round 13
// baseline (37756.342 us; speedup 1.0000x reference)
//
#include <hip/hip_runtime.h>
#include <hip/hip_cooperative_groups.h>

namespace cg = cooperative_groups;

#define B_ 128
#define S_ 256
#define H_ 1024
#define V_ 512
#define T_ 128
#define G4 4096

typedef __attribute__((ext_vector_type(8))) short bf16x8;
typedef __attribute__((ext_vector_type(4))) float f32x4;
typedef __attribute__((ext_vector_type(2))) float f32x2;

// ---------- helpers ----------
__device__ __forceinline__ float bf2f(unsigned short x) {
    unsigned int u = ((unsigned int)x) << 16;
    return __builtin_bit_cast(float, u);
}
__device__ __forceinline__ unsigned short f2b(float f) {
    unsigned int u = __builtin_bit_cast(unsigned int, f);
    u = u + 0x7fffu + ((u >> 16) & 1u);
    return (unsigned short)(u >> 16);
}
__device__ __forceinline__ float ftanh(float x) {
    float e = __expf(2.f * x);
    return 1.f - 2.f * __builtin_amdgcn_rcpf(e + 1.f);
}
__device__ __forceinline__ float fsigm(float x) {
    return __builtin_amdgcn_rcpf(1.f + __expf(-x));
}
__device__ __forceinline__ void gll16(const void* g, void* l) {
    __builtin_amdgcn_global_load_lds(
        (const __attribute__((address_space(1))) unsigned int*)g,
        (__attribute__((address_space(3))) unsigned int*)l, 16, 0, 0);
}

// ---------- fp8 e4m3fn (OCP) helpers ----------
__device__ __forceinline__ unsigned char sw_e4m3(float f) {
    unsigned int ub = __builtin_bit_cast(unsigned int, f);
    unsigned char s = (unsigned char)((ub >> 24) & 0x80);
    float a = fabsf(f);
    if (!(a < 464.f)) return (unsigned char)(s | 0x7E);
    if (a < 0.0009765625f) return s;
    if (a < 0.015625f) {
        int m = (int)(a * 512.f + 0.5f);
        if (m >= 8) return (unsigned char)(s | 0x08);
        return (unsigned char)(s | m);
    }
    unsigned int u = __builtin_bit_cast(unsigned int, a);
    u += 0x7FFFF + ((u >> 20) & 1);
    int e = (int)(u >> 23) - 127;
    if (e > 8) return (unsigned char)(s | 0x7E);
    unsigned int man = (u >> 20) & 7;
    return (unsigned char)(s | ((unsigned int)(e + 7) << 3) | man);
}
__device__ __forceinline__ float sw_f_e4m3(unsigned int byte) {
    unsigned int s = (byte & 0x80u) << 24;
    unsigned int em = byte & 0x7Fu;
    float v;
    if (em >= 8u) v = __builtin_bit_cast(float, (em + 960u) << 20);
    else v = (float)em * 0.001953125f;
    return __builtin_bit_cast(float, __builtin_bit_cast(unsigned int, v) | s);
}
__device__ __forceinline__ unsigned char enc1(float a) {
#if __has_builtin(__builtin_amdgcn_cvt_pk_fp8_f32)
    unsigned int w = __builtin_amdgcn_cvt_pk_fp8_f32(a, a, 0u, false);
    return (unsigned char)(w & 0xff);
#else
    return sw_e4m3(a);
#endif
}
__device__ __forceinline__ unsigned int enc4(float a, float b, float c, float d) {
#if __has_builtin(__builtin_amdgcn_cvt_pk_fp8_f32)
    unsigned int w = 0;
    w = __builtin_amdgcn_cvt_pk_fp8_f32(a, b, w, false);
    w = __builtin_amdgcn_cvt_pk_fp8_f32(c, d, w, true);
    return w;
#else
    return (unsigned int)sw_e4m3(a) | ((unsigned int)sw_e4m3(b) << 8) |
           ((unsigned int)sw_e4m3(c) << 16) | ((unsigned int)sw_e4m3(d) << 24);
#endif
}
__device__ __forceinline__ void dec4(unsigned int w, float* o) {
#if __has_builtin(__builtin_amdgcn_cvt_pk_f32_fp8)
    f32x2 lo = __builtin_amdgcn_cvt_pk_f32_fp8(w, false);
    f32x2 hi = __builtin_amdgcn_cvt_pk_f32_fp8(w, true);
    o[0] = lo.x; o[1] = lo.y; o[2] = hi.x; o[3] = hi.y;
#else
    o[0] = sw_f_e4m3(w & 0xff); o[1] = sw_f_e4m3((w >> 8) & 0xff);
    o[2] = sw_f_e4m3((w >> 16) & 0xff); o[3] = sw_f_e4m3(w >> 24);
#endif
}

// ---------- small precompute kernels ----------
__global__ void f32_to_bf16_x4(const float4* __restrict__ in, ushort4* __restrict__ out, int n4) {
    int i = blockIdx.x * 256 + threadIdx.x;
    if (i < n4) {
        float4 v = in[i];
        ushort4 o;
        o.x = f2b(v.x); o.y = f2b(v.y); o.z = f2b(v.z); o.w = f2b(v.w);
        out[i] = o;
    }
}

__global__ void f32_to_fp8_x4(const float4* __restrict__ in, unsigned int* __restrict__ out, int n4) {
    int i = blockIdx.x * 256 + threadIdx.x;
    if (i < n4) {
        float4 v = in[i];
        out[i] = enc4(v.x, v.y, v.z, v.w);
    }
}

__global__ void cvt_gather(const float* __restrict__ src, int src_ld, int coff,
                           unsigned short* __restrict__ dst, int perm) {
    int i = blockIdx.x * 256 + threadIdx.x;
    int r = i >> 8;
    int c = (i & 255) * 4;
    int sr = perm ? (((r & 3) << 10) + (r >> 2)) : r;
    float4 v = *reinterpret_cast<const float4*>(src + (size_t)sr * src_ld + coff + c);
    ushort4 o;
    o.x = f2b(v.x); o.y = f2b(v.y); o.z = f2b(v.z); o.w = f2b(v.w);
    *reinterpret_cast<ushort4*>(dst + (size_t)r * 1024 + c) = o;
}

__global__ void build_toks(const int* __restrict__ target, int* __restrict__ toks) {
    int idx = blockIdx.x * 256 + threadIdx.x;
    if (idx < T_ * B_) {
        int t = idx / B_, b = idx % B_;
        toks[idx] = (t == 0) ? 0 : target[b * T_ + t - 1];
    }
}

__global__ void build_bsum(const float* __restrict__ b_ih, const float* __restrict__ b_hh,
                           float* __restrict__ bsum) {
    int j = blockIdx.x * 256 + threadIdx.x;
    if (j < G4) {
        int pj = ((j & 3) << 10) + (j >> 2);
        bsum[j] = b_ih[pj] + b_hh[pj];
    }
}

// ---------- 64x64-tile bf16 MFMA GEMM (precompute only), BK=128, depth-2 counted vmcnt ----------
template<int MODE>
__global__ __launch_bounds__(256) void gemm_mf(
    const unsigned short* __restrict__ A,
    const unsigned short* __restrict__ Bw,
    int K, int ldb, int ldc,
    float* __restrict__ C, unsigned char* __restrict__ C8,
    const float* __restrict__ bias)
{
    __shared__ unsigned short As[2 * 8192];
    __shared__ unsigned short Bs[2 * 8192];
    const int tid = threadIdx.x;
    const int lane = tid & 63;
    const int wv = tid >> 6;
    const int m0 = blockIdx.x * 64;
    const int n0 = blockIdx.y * 64;

    const unsigned short* ga[4];
    const unsigned short* gb[4];
    #pragma unroll
    for (int j = 0; j < 4; ++j) {
        int ci = tid + 256 * j;
        int row = ci >> 4;
        int src = (ci & 15) ^ (row & 7);
        ga[j] = A + (size_t)(m0 + row) * K + src * 8;
        gb[j] = Bw + (size_t)(n0 + row) * ldb + src * 8;
    }

    f32x4 acc[2][2] = {};
    const int r0 = (wv >> 1) * 32;
    const int cq0 = (wv & 1) * 32;
    const int fr = lane & 15;
    const int kg = lane >> 4;

    auto stage = [&](int k0, int p) {
        #pragma unroll
        for (int j = 0; j < 4; ++j) {
            gll16(ga[j] + k0, As + p * 8192 + j * 2048 + wv * 512);
            gll16(gb[j] + k0, Bs + p * 8192 + j * 2048 + wv * 512);
        }
    };

    stage(0, 0);
    stage(128, 1);
    int p = 0;
    for (int k0 = 0; k0 < K; k0 += 128) {
        if (k0 + 128 < K) {
            asm volatile("s_waitcnt vmcnt(8)" ::: "memory");
        } else {
            asm volatile("s_waitcnt vmcnt(0)" ::: "memory");
        }
        __builtin_amdgcn_sched_barrier(0);
        __builtin_amdgcn_s_barrier();
        __builtin_amdgcn_sched_barrier(0);
        const unsigned short* Ab = As + p * 8192;
        const unsigned short* Bb = Bs + p * 8192;
        bf16x8 af[2][4], bfr[2][4];
        #pragma unroll
        for (int f = 0; f < 2; ++f)
            #pragma unroll
            for (int kh = 0; kh < 4; ++kh) {
                int ra = r0 + f * 16 + fr;
                af[f][kh] = *(const bf16x8*)&Ab[ra * 128 + (((kh * 4 + kg) ^ (ra & 7)) << 3)];
                int rb = cq0 + f * 16 + fr;
                bfr[f][kh] = *(const bf16x8*)&Bb[rb * 128 + (((kh * 4 + kg) ^ (rb & 7)) << 3)];
            }
        asm volatile("s_waitcnt lgkmcnt(0)" ::: "memory");
        __builtin_amdgcn_sched_barrier(0);
        __builtin_amdgcn_s_barrier();
        __builtin_amdgcn_sched_barrier(0);
        if (k0 + 256 < K) stage(k0 + 256, p);
        __builtin_amdgcn_s_setprio(1);
        #pragma unroll
        for (int f = 0; f < 2; ++f)
            #pragma unroll
            for (int g = 0; g < 2; ++g)
                #pragma unroll
                for (int kh = 0; kh < 4; ++kh)
                    acc[f][g] = __builtin_amdgcn_mfma_f32_16x16x32_bf16(
                        af[f][kh], bfr[g][kh], acc[f][g], 0, 0, 0);
        __builtin_amdgcn_s_setprio(0);
        p ^= 1;
    }

    const int erow = (lane >> 4) * 4;
    const int ecol = lane & 15;
    #pragma unroll
    for (int f = 0; f < 2; ++f) {
        #pragma unroll
        for (int g = 0; g < 2; ++g) {
            #pragma unroll
            for (int r = 0; r < 4; ++r) {
                int row = m0 + r0 + f * 16 + erow + r;
                int col = n0 + cq0 + g * 16 + ecol;
                float v = acc[f][g][r] + bias[col];
                if (MODE == 0) C[(size_t)row * ldc + col] = v;
                else C8[(size_t)row * ldc + col] = enc1(v);
            }
        }
    }
}

// ---------- shared device phase: 64x32-tile bf16 MFMA GEMM, K=1024, depth-3 ----------
// MODE 2: col<1024 -> Cq=q(+bias); else gates(+Pemb[tok])
// MODE 4: gates-acc + fused LSTM pointwise epilogue (Cb = h out bf16)
// MODE 0: C = v + bias[col] (ldc = V_)  [batched logits]
template<int MODE>
__device__ void gemm_tile(
    unsigned short* As, unsigned short* Bs,
    const unsigned short* __restrict__ A,
    const unsigned short* __restrict__ Bw,
    int m0, int n0,
    float* __restrict__ C, unsigned short* __restrict__ Cb,
    const float* __restrict__ bias,
    const float* __restrict__ Pemb,
    const int* __restrict__ toks,
    float* __restrict__ Cq,
    float* __restrict__ Lg,
    int flag)
{
    const int tid = threadIdx.x;
    const int lane = tid & 63;
    const int wv = tid >> 6;
    const int K = 1024;

    const unsigned short* ga[4];
    const unsigned short* gb[2];
    #pragma unroll
    for (int j = 0; j < 4; ++j) {
        int ci = tid + 256 * j;
        int row = ci >> 4;
        int src = (ci & 15) ^ (row & 7);
        ga[j] = A + (size_t)(m0 + row) * K + src * 8;
    }
    #pragma unroll
    for (int j = 0; j < 2; ++j) {
        int ci = tid + 256 * j;
        int row = ci >> 4;
        int src = (ci & 15) ^ (row & 7);
        gb[j] = Bw + (size_t)(n0 + row) * K + src * 8;
    }

    f32x4 acc[2] = {};
    const int r0 = (wv >> 1) * 32;
    const int c0 = (wv & 1) * 16;
    const int fr = lane & 15;
    const int kg = lane >> 4;

    auto stage = [&](int k0, int p) {
        #pragma unroll
        for (int j = 0; j < 4; ++j)
            gll16(ga[j] + k0, As + p * 8192 + j * 2048 + wv * 512);
        #pragma unroll
        for (int j = 0; j < 2; ++j)
            gll16(gb[j] + k0, Bs + p * 4096 + j * 2048 + wv * 512);
    };

    stage(0, 0);
    stage(128, 1);
    stage(256, 2);
    int p = 0;
    for (int k0 = 0; k0 < K; k0 += 128) {
        if (k0 + 256 < K) {
            asm volatile("s_waitcnt vmcnt(12)" ::: "memory");
        } else if (k0 + 128 < K) {
            asm volatile("s_waitcnt vmcnt(6)" ::: "memory");
        } else {
            asm volatile("s_waitcnt vmcnt(0)" ::: "memory");
        }
        __builtin_amdgcn_sched_barrier(0);
        __builtin_amdgcn_s_barrier();
        __builtin_amdgcn_sched_barrier(0);
        const unsigned short* Ab = As + p * 8192;
        const unsigned short* Bb = Bs + p * 4096;
        bf16x8 af[2][4], bfr[4];
        #pragma unroll
        for (int kh = 0; kh < 4; ++kh) {
            #pragma unroll
            for (int f = 0; f < 2; ++f) {
                int ra = r0 + f * 16 + fr;
                af[f][kh] = *(const bf16x8*)&Ab[ra * 128 + (((kh * 4 + kg) ^ (ra & 7)) << 3)];
            }
            int rb = c0 + fr;
            bfr[kh] = *(const bf16x8*)&Bb[rb * 128 + (((kh * 4 + kg) ^ (rb & 7)) << 3)];
        }
        asm volatile("s_waitcnt lgkmcnt(0)" ::: "memory");
        __builtin_amdgcn_sched_barrier(0);
        __builtin_amdgcn_s_barrier();
        __builtin_amdgcn_sched_barrier(0);
        if (k0 + 384 < K) stage(k0 + 384, p);
        __builtin_amdgcn_s_setprio(1);
        #pragma unroll
        for (int f = 0; f < 2; ++f)
            #pragma unroll
            for (int kh = 0; kh < 4; ++kh)
                acc[f] = __builtin_amdgcn_mfma_f32_16x16x32_bf16(
                    af[f][kh], bfr[kh], acc[f], 0, 0, 0);
        __builtin_amdgcn_s_setprio(0);
        p = (p == 2) ? 0 : p + 1;
    }

    const int erow = (lane >> 4) * 4;
    const int ecol = lane & 15;

    if constexpr (MODE == 4) {
        float* Lt = (float*)As;   // reuse LDS (K-loop done)
        __syncthreads();
        #pragma unroll
        for (int f = 0; f < 2; ++f)
            #pragma unroll
            for (int r = 0; r < 4; ++r)
                Lt[(r0 + f * 16 + erow + r) * 32 + c0 + ecol] = acc[f][r];
        __syncthreads();
        #pragma unroll
        for (int i = 0; i < 2; ++i) {
            int pi = tid + 256 * i;
            int r = pi >> 3, u = pi & 7;
            int b = m0 + r;
            int hh = (n0 >> 2) + u;
            f32x4 gv = *reinterpret_cast<const f32x4*>(&Lt[r * 32 + u * 4]);
            const float* gp = C + (size_t)b * G4 + n0 + u * 4;
            float iv = gv[0] + gp[0];
            float fv = gv[1] + gp[1];
            float gg = gv[2] + gp[2];
            float ov = gv[3] + gp[3];
            int ci = b * H_ + hh;
            float cn = fsigm(fv) * Cq[ci] + fsigm(iv) * ftanh(gg);
            float hn = fsigm(ov) * ftanh(cn);
            Cq[ci] = cn;
            Cb[ci] = f2b(hn);
            if (flag) Lg[ci] = hn;
        }
        __syncthreads();
    } else {
        #pragma unroll
        for (int f = 0; f < 2; ++f) {
            #pragma unroll
            for (int r = 0; r < 4; ++r) {
                int row = m0 + r0 + f * 16 + erow + r;
                int col = n0 + c0 + ecol;
                float v = acc[f][r];
                if (MODE == 0) {
                    C[(size_t)row * V_ + col] = v + bias[col];
                } else {  // MODE 2: q | gates
                    if (col < H_) {
                        Cq[(size_t)row * H_ + col] = v + bias[col];
                    } else {
                        int cg = col - H_;
                        C[(size_t)row * G4 + cg] = v + Pemb[(size_t)toks[row] * G4 + cg];
                    }
                }
            }
        }
    }
}

// ---------- shared device phase: attention energies + raw-exp partial context ----------
// Processes `count` consecutive (b,sh) tiles starting at `base` (same b for all).
__device__ void attn_tiles(
    unsigned char* smem, int base, int count,
    const unsigned int* __restrict__ kp8,
    const float* __restrict__ q,
    const float* __restrict__ Va,
    const unsigned int* __restrict__ encb8,
    float* __restrict__ es_g,
    unsigned short* __restrict__ pctx)
{
    float* qs = (float*)smem;
    float* vas = qs + H_;
    float* pe = vas + H_;
    const int tid = threadIdx.x;
    const int lane = tid & 63;
    const int wv = tid >> 6;
    const int b = base >> 4;

    *reinterpret_cast<float4*>(&qs[tid * 4]) =
        *reinterpret_cast<const float4*>(&q[(size_t)b * H_ + tid * 4]);
    *reinterpret_cast<float4*>(&vas[tid * 4]) =
        *reinterpret_cast<const float4*>(&Va[tid * 4]);
    __syncthreads();

    for (int c = 0; c < count; ++c) {
        const int sh = (base + c) & 15;
        #pragma unroll
        for (int si = 0; si < 4; ++si) {
            int s_loc = wv * 4 + si;
            const uint4* kr = reinterpret_cast<const uint4*>(
                kp8 + (size_t)(b * S_ + sh * 16 + s_loc) * 256);
            uint4 u = kr[lane];
            const int h0 = lane * 16;
            float d[4];
            float acc = 0.f;
            dec4(u.x, d);
            acc += vas[h0 + 0] * ftanh(qs[h0 + 0] + d[0]);
            acc += vas[h0 + 1] * ftanh(qs[h0 + 1] + d[1]);
            acc += vas[h0 + 2] * ftanh(qs[h0 + 2] + d[2]);
            acc += vas[h0 + 3] * ftanh(qs[h0 + 3] + d[3]);
            dec4(u.y, d);
            acc += vas[h0 + 4] * ftanh(qs[h0 + 4] + d[0]);
            acc += vas[h0 + 5] * ftanh(qs[h0 + 5] + d[1]);
            acc += vas[h0 + 6] * ftanh(qs[h0 + 6] + d[2]);
            acc += vas[h0 + 7] * ftanh(qs[h0 + 7] + d[3]);
            dec4(u.z, d);
            acc += vas[h0 + 8] * ftanh(qs[h0 + 8] + d[0]);
            acc += vas[h0 + 9] * ftanh(qs[h0 + 9] + d[1]);
            acc += vas[h0 + 10] * ftanh(qs[h0 + 10] + d[2]);
            acc += vas[h0 + 11] * ftanh(qs[h0 + 11] + d[3]);
            dec4(u.w, d);
            acc += vas[h0 + 12] * ftanh(qs[h0 + 12] + d[0]);
            acc += vas[h0 + 13] * ftanh(qs[h0 + 13] + d[1]);
            acc += vas[h0 + 14] * ftanh(qs[h0 + 14] + d[2]);
            acc += vas[h0 + 15] * ftanh(qs[h0 + 15] + d[3]);
            #pragma unroll
            for (int off = 32; off; off >>= 1) acc += __shfl_down(acc, off);
            if (lane == 0) {
                pe[s_loc] = __expf(acc);
                es_g[(size_t)b * S_ + sh * 16 + s_loc] = acc;
            }
        }
        __syncthreads();

        const int cc0 = tid * 4;
        float ax = 0.f, ay = 0.f, az = 0.f, aw = 0.f;
        #pragma unroll
        for (int sl = 0; sl < 16; ++sl) {
            unsigned int u = encb8[(size_t)(b * S_ + sh * 16 + sl) * 256 + tid];
            float d[4];
            dec4(u, d);
            float w = pe[sl];
            ax += w * d[0];
            ay += w * d[1];
            az += w * d[2];
            aw += w * d[3];
        }
        ushort4 o4;
        o4.x = f2b(ax); o4.y = f2b(ay); o4.z = f2b(az); o4.w = f2b(aw);
        *reinterpret_cast<ushort4*>(&pctx[((size_t)b * 16 + sh) * H_ + cc0]) = o4;
        __syncthreads();   // pe reused next chunk
    }
}

// ---------- shared device phase: combine (Z-sum + attn store + ctx) ----------
__device__ void comb_tile(
    unsigned char* smem, int bid, int t,
    const float* __restrict__ es_g,
    const unsigned short* __restrict__ pctx,
    unsigned short* __restrict__ ctxb,
    float* __restrict__ attnOut)
{
    float* red = (float*)smem;
    const int b = bid >> 1;
    const int hh = bid & 1;
    const int tid = threadIdx.x;
    const int lane = tid & 63;
    const int wv = tid >> 6;

    float ex = __expf(es_g[(size_t)b * S_ + tid]);
    float sm = ex;
    #pragma unroll
    for (int off = 32; off; off >>= 1) sm += __shfl_xor(sm, off);
    if (lane == 0) red[wv] = sm;
    __syncthreads();
    sm = red[0] + red[1] + red[2] + red[3];
    float rZ = __builtin_amdgcn_rcpf(sm);
    if (hh == 0) attnOut[((size_t)(b * T_ + t)) * S_ + tid] = ex * rZ;

    const int c0 = hh * 512 + tid * 2;
    float a0 = 0.f, a1 = 0.f;
    #pragma unroll
    for (int blk = 0; blk < 16; ++blk) {
        ushort2 pv = *reinterpret_cast<const ushort2*>(
            &pctx[((size_t)b * 16 + blk) * H_ + c0]);
        a0 += bf2f(pv.x); a1 += bf2f(pv.y);
    }
    ushort2 o; o.x = f2b(a0 * rZ); o.y = f2b(a1 * rZ);
    *reinterpret_cast<ushort2*>(&ctxb[(size_t)b * H_ + c0]) = o;
    __syncthreads();
}

// ---------- args for the persistent cooperative kernel ----------
struct MegaArgs {
    const unsigned int* kp8;
    const unsigned int* encb8;
    const unsigned short* Wcat_b;   // [Wa; W_hh(perm)] 5120 x 1024
    const unsigned short* Wih2_b;   // 4096 x 1024
    const unsigned short* hb0;
    unsigned short* hall;
    float* qbuf;
    float* gates;
    const float* Pemb;
    const int* toks;
    float* cbuf;
    unsigned short* ctxb;
    float* es_g;
    unsigned short* pctx;
    float* attn;
    float* hid;
    const float* Va;
    const float* Wa_b;
};

// ---------- persistent cooperative kernel: full decode loop ----------
__global__ __launch_bounds__(256, 2) void mega(MegaArgs a) {
    cg::grid_group grid = cg::this_grid();
    __shared__ __align__(16) unsigned char smem[73728];
    unsigned short* As = (unsigned short*)smem;            // 48 KB (3 x 16KB)
    unsigned short* Bs = (unsigned short*)(smem + 49152);  // 24 KB (3 x 8KB)
    const int bid = blockIdx.x;

    for (int t = 0; t < T_; ++t) {
        const unsigned short* hprev = (t == 0) ? a.hb0 : a.hall + (size_t)(t - 1) * B_ * H_;
        // P1: q + h-gates GEMM (320 tiles)
        if (bid < 320) {
            int m0 = (bid & 1) * 64;
            int n0 = (bid >> 1) * 32;
            gemm_tile<2>(As, Bs, hprev, a.Wcat_b, m0, n0,
                         a.gates, nullptr, a.Wa_b, a.Pemb, a.toks + t * B_,
                         a.qbuf, nullptr, 0);
        }
        grid.sync();
        // P2: attention energies + partial ctx (2048 tiles, 4 per block)
        attn_tiles(smem, bid * 4, 4, a.kp8, a.qbuf, a.Va, a.encb8, a.es_g, a.pctx);
        grid.sync();
        // P3: combine (256 tiles)
        if (bid < 256) comb_tile(smem, bid, t, a.es_g, a.pctx, a.ctxb, a.attn);
        grid.sync();
        // P4: ctx-gates GEMM + LSTM (256 tiles)
        if (bid < 256) {
            int m0 = (bid & 1) * 64;
            int n0 = (bid >> 1) * 32;
            gemm_tile<4>(As, Bs, a.ctxb, a.Wih2_b, m0, n0,
                         a.gates, a.hall + (size_t)t * B_ * H_, nullptr, nullptr, nullptr,
                         a.cbuf, a.hid, t == T_ - 1);
        }
        grid.sync();
    }
}

// ---------- fallback per-step kernels (R12 structure, wrapping the device phases) ----------
__global__ __launch_bounds__(256) void gemm1_k(
    const unsigned short* A, const unsigned short* Bw,
    float* C, const float* bias, const float* Pemb, const int* toks, float* Cq)
{
    __shared__ __align__(16) unsigned char smem[73728];
    gemm_tile<2>((unsigned short*)smem, (unsigned short*)(smem + 49152),
                 A, Bw, blockIdx.x * 64, blockIdx.y * 32, C, nullptr, bias, Pemb, toks, Cq,
                 nullptr, 0);
}
__global__ __launch_bounds__(256) void gemm2_k(
    const unsigned short* A, const unsigned short* Bw,
    float* C, unsigned short* Cb, float* Cq, float* Lg, int flag)
{
    __shared__ __align__(16) unsigned char smem[73728];
    gemm_tile<4>((unsigned short*)smem, (unsigned short*)(smem + 49152),
                 A, Bw, blockIdx.x * 64, blockIdx.y * 32, C, Cb, nullptr, nullptr, nullptr,
                 Cq, Lg, flag);
}
__global__ __launch_bounds__(256) void attn_e_k(
    const unsigned int* kp8, const float* q, const float* Va,
    const unsigned int* encb8, float* es_g, unsigned short* pctx)
{
    __shared__ __align__(16) unsigned char smem[16384];
    attn_tiles(smem, blockIdx.x * 16 + blockIdx.y, 1, kp8, q, Va, encb8, es_g, pctx);
}
__global__ __launch_bounds__(256) void comb_k(
    const float* es_g, const unsigned short* pctx,
    unsigned short* ctxb, float* attnOut, int t)
{
    __shared__ __align__(16) unsigned char smem[64];
    comb_tile(smem, blockIdx.x, t, es_g, pctx, ctxb, attnOut);
}

// ---------- batched logits GEMM wrapper (final) ----------
__global__ __launch_bounds__(256) void logits_k(
    const unsigned short* A, const unsigned short* Bw, float* C, const float* bias)
{
    __shared__ __align__(16) unsigned char smem[73728];
    gemm_tile<0>((unsigned short*)smem, (unsigned short*)(smem + 49152),
                 A, Bw, blockIdx.x * 64, blockIdx.y * 32, C, nullptr, bias, nullptr, nullptr,
                 nullptr, nullptr, 0);
}

// ---------- batched log-softmax over all (t,b) rows ----------
__global__ __launch_bounds__(256) void lsm_all(
    const float* __restrict__ lgall,   // [(t*B+b)][V]
    float* __restrict__ lp)            // [B,T,V]
{
    int r = blockIdx.x;
    int t = r >> 7, b = r & (B_ - 1);
    int tid = threadIdx.x;
    int lane = tid & 63, wv = tid >> 6;
    __shared__ float red[4];
    float a0 = lgall[(size_t)r * V_ + tid];
    float a1 = lgall[(size_t)r * V_ + 256 + tid];
    float mx = fmaxf(a0, a1);
    #pragma unroll
    for (int off = 32; off; off >>= 1) mx = fmaxf(mx, __shfl_xor(mx, off));
    if (lane == 0) red[wv] = mx;
    __syncthreads();
    mx = fmaxf(fmaxf(red[0], red[1]), fmaxf(red[2], red[3]));
    float sm = __expf(a0 - mx) + __expf(a1 - mx);
    #pragma unroll
    for (int off = 32; off; off >>= 1) sm += __shfl_xor(sm, off);
    __syncthreads();
    if (lane == 0) red[wv] = sm;
    __syncthreads();
    sm = red[0] + red[1] + red[2] + red[3];
    float lse = mx + __logf(sm);
    size_t off = ((size_t)b * T_ + t) * V_;
    lp[off + tid] = a0 - lse;
    lp[off + tid + 256] = a1 - lse;
}

// ---------- launch ----------
extern "C" void kernel_launch(void* const* d_in, const int* in_sizes, int n_in,
                              void* d_out, int out_size, void* d_ws, size_t ws_size,
                              hipStream_t stream) {
    const float* enc   = (const float*)d_in[0];
    const float* h0    = (const float*)d_in[1];
    const float* c0    = (const float*)d_in[2];
    const int*   targ  = (const int*)d_in[3];
    const float* emb   = (const float*)d_in[5];
    const float* Wa_w  = (const float*)d_in[6];
    const float* Wa_b  = (const float*)d_in[7];
    const float* Ua_w  = (const float*)d_in[8];
    const float* Ua_b  = (const float*)d_in[9];
    const float* Va_w  = (const float*)d_in[10];
    const float* W_ih  = (const float*)d_in[12];
    const float* W_hh  = (const float*)d_in[13];
    const float* b_ih  = (const float*)d_in[14];
    const float* b_hh  = (const float*)d_in[15];
    const float* out_w = (const float*)d_in[16];
    const float* out_b = (const float*)d_in[17];

    float* out  = (float*)d_out;
    float* lp   = out;                          // [B,T,V]
    float* hid  = out + (size_t)B_ * T_ * V_;   // [1,B,H]
    float* attn = hid + (size_t)B_ * H_;        // [B,T,S]

    char* w = (char*)d_ws;
    auto alloc = [&](size_t bytes) {
        char* p = w;
        w += (bytes + 255) & ~(size_t)255;
        return p;
    };
    const size_t NKP = (size_t)B_ * S_ * H_;
    unsigned int* kp8      = (unsigned int*)alloc(NKP);
    unsigned int* encb8    = (unsigned int*)alloc(NKP);
    char* uni = alloc(NKP * 2);   // encb (precompute) -> reused as hall + lgall
    unsigned short* encb = (unsigned short*)uni;
    unsigned short* hall = (unsigned short*)uni;
    float* lgall = (float*)(uni + (size_t)T_ * B_ * H_ * 2);
    unsigned short* Wcat_b = (unsigned short*)alloc((size_t)5120 * H_ * 2);
    unsigned short* Wih1_b = (unsigned short*)alloc((size_t)G4 * H_ * 2);
    unsigned short* Wih2_b = (unsigned short*)alloc((size_t)G4 * H_ * 2);
    unsigned short* Uaw_b  = (unsigned short*)alloc((size_t)H_ * H_ * 2);
    unsigned short* emb_b  = (unsigned short*)alloc((size_t)V_ * H_ * 2);
    unsigned short* owb_b  = (unsigned short*)alloc((size_t)V_ * H_ * 2);
    unsigned short* hb0    = (unsigned short*)alloc((size_t)B_ * H_ * 2);
    unsigned short* ctxb   = (unsigned short*)alloc((size_t)B_ * H_ * 2);
    float* Pemb  = (float*)alloc((size_t)V_ * G4 * 4);
    float* bsumP = (float*)alloc((size_t)G4 * 4);
    int*   toks  = (int*)alloc((size_t)T_ * B_ * 4);
    float* cbuf  = (float*)alloc((size_t)B_ * H_ * 4);
    float* qbuf  = (float*)alloc((size_t)B_ * H_ * 4);
    float* gates = (float*)alloc((size_t)B_ * G4 * 4);
    float* es_g  = (float*)alloc((size_t)B_ * S_ * 4);
    unsigned short* pctx = (unsigned short*)alloc((size_t)B_ * 16 * H_ * 2);
    if ((size_t)(w - (char*)d_ws) > ws_size) return;

    auto cvt = [&](const float* src, unsigned short* dst, size_t n) {
        int n4 = (int)(n / 4);
        f32_to_bf16_x4<<<(n4 + 255) / 256, 256, 0, stream>>>((const float4*)src, (ushort4*)dst, n4);
    };

    // precompute
    cvt(enc, encb, NKP);
    f32_to_fp8_x4<<<(int)(NKP / 4 + 255) / 256, 256, 0, stream>>>(
        (const float4*)enc, encb8, (int)(NKP / 4));
    cvt(Ua_w, Uaw_b, (size_t)H_ * H_);
    cvt(emb, emb_b, (size_t)V_ * H_);
    cvt(h0, hb0, (size_t)B_ * H_);
    cvt_gather<<<1024, 256, 0, stream>>>(Wa_w, H_, 0, Wcat_b, 0);
    cvt_gather<<<4096, 256, 0, stream>>>(W_hh, H_, 0, Wcat_b + (size_t)1024 * H_, 1);
    cvt_gather<<<512, 256, 0, stream>>>(out_w, H_, 0, owb_b, 0);
    cvt_gather<<<4096, 256, 0, stream>>>(W_ih, 2 * H_, 0, Wih1_b, 1);
    cvt_gather<<<4096, 256, 0, stream>>>(W_ih, 2 * H_, H_, Wih2_b, 1);
    build_toks<<<(T_ * B_ + 255) / 256, 256, 0, stream>>>(targ, toks);
    build_bsum<<<(G4 + 255) / 256, 256, 0, stream>>>(b_ih, b_hh, bsumP);
    hipMemcpyAsync(cbuf, c0, (size_t)B_ * H_ * 4, hipMemcpyDeviceToDevice, stream);

    // keys_proj: kp8 = fp8(encb @ Ua_w^T + Ua_b)
    gemm_mf<1><<<dim3((B_ * S_) / 64, H_ / 64), 256, 0, stream>>>(
        encb, Uaw_b, H_, H_, H_, nullptr, (unsigned char*)kp8, Ua_b);
    // Pemb (permuted): emb @ W_ih[:, :H](perm)^T + bsumP
    gemm_mf<0><<<dim3(V_ / 64, G4 / 64), 256, 0, stream>>>(
        emb_b, Wih1_b, H_, H_, G4, Pemb, nullptr, bsumP);

    // decode loop: single persistent cooperative kernel (fallback: 4 launches/step)
    MegaArgs ma;
    ma.kp8 = kp8; ma.encb8 = encb8; ma.Wcat_b = Wcat_b; ma.Wih2_b = Wih2_b;
    ma.hb0 = hb0; ma.hall = hall; ma.qbuf = qbuf; ma.gates = gates;
    ma.Pemb = Pemb; ma.toks = toks; ma.cbuf = cbuf; ma.ctxb = ctxb;
    ma.es_g = es_g; ma.pctx = pctx; ma.attn = attn; ma.hid = hid;
    ma.Va = Va_w; ma.Wa_b = Wa_b;
    void* kparams[] = { (void*)&ma };
    hipError_t ce = hipLaunchCooperativeKernel(
        (const void*)mega, dim3(512), dim3(256), kparams, 0, stream);
    if (ce != hipSuccess) {
        for (int t = 0; t < T_; ++t) {
            const unsigned short* hprev = (t == 0) ? hb0 : hall + (size_t)(t - 1) * B_ * H_;
            gemm1_k<<<dim3(2, 160), 256, 0, stream>>>(
                hprev, Wcat_b, gates, Wa_b, Pemb, toks + t * B_, qbuf);
            attn_e_k<<<dim3(B_, 16), 256, 0, stream>>>(kp8, qbuf, Va_w, encb8, es_g, pctx);
            comb_k<<<256, 256, 0, stream>>>(es_g, pctx, ctxb, attn, t);
            gemm2_k<<<dim3(2, 128), 256, 0, stream>>>(
                ctxb, Wih2_b, gates, hall + (size_t)t * B_ * H_, cbuf, hid, t == T_ - 1);
        }
    }

    // batched logits over all steps + log-softmax
    logits_k<<<dim3((T_ * B_) / 64, V_ / 32), 256, 0, stream>>>(hall, owb_b, lgall, out_b);
    lsm_all<<<T_ * B_, 256, 0, stream>>>(lgall, lp);
}

// Round 14
// 7582.131 us; speedup vs baseline: 4.9796x; 4.9796x over previous
//
#include <hip/hip_runtime.h>

#define B_ 128
#define S_ 256
#define H_ 1024
#define V_ 512
#define T_ 128
#define G4 4096

typedef __attribute__((ext_vector_type(8))) short bf16x8;
typedef __attribute__((ext_vector_type(4))) float f32x4;
typedef __attribute__((ext_vector_type(2))) float f32x2;

// ---------- helpers ----------
__device__ __forceinline__ float bf2f(unsigned short x) {
    unsigned int u = ((unsigned int)x) << 16;
    return __builtin_bit_cast(float, u);
}
__device__ __forceinline__ unsigned short f2b(float f) {
    unsigned int u = __builtin_bit_cast(unsigned int, f);
    u = u + 0x7fffu + ((u >> 16) & 1u);
    return (unsigned short)(u >> 16);
}
__device__ __forceinline__ float ftanh(float x) {
    float e = __expf(2.f * x);
    return 1.f - 2.f * __builtin_amdgcn_rcpf(e + 1.f);
}
__device__ __forceinline__ float fsigm(float x) {
    return __builtin_amdgcn_rcpf(1.f + __expf(-x));
}
__device__ __forceinline__ void gll16(const void* g, void* l) {
    __builtin_amdgcn_global_load_lds(
        (const __attribute__((address_space(1))) unsigned int*)g,
        (__attribute__((address_space(3))) unsigned int*)l, 16, 0, 0);
}

// ---------- fp8 e4m3fn (OCP) helpers ----------
__device__ __forceinline__ unsigned char sw_e4m3(float f) {
    unsigned int ub = __builtin_bit_cast(unsigned int, f);
    unsigned char s = (unsigned char)((ub >> 24) & 0x80);
    float a = fabsf(f);
    if (!(a < 464.f)) return (unsigned char)(s | 0x7E);
    if (a < 0.0009765625f) return s;
    if (a < 0.015625f) {
        int m = (int)(a * 512.f + 0.5f);
        if (m >= 8) return (unsigned char)(s | 0x08);
        return (unsigned char)(s | m);
    }
    unsigned int u = __builtin_bit_cast(unsigned int, a);
    u += 0x7FFFF + ((u >> 20) & 1);
    int e = (int)(u >> 23) - 127;
    if (e > 8) return (unsigned char)(s | 0x7E);
    unsigned int man = (u >> 20) & 7;
    return (unsigned char)(s | ((unsigned int)(e + 7) << 3) | man);
}
__device__ __forceinline__ float sw_f_e4m3(unsigned int byte) {
    unsigned int s = (byte & 0x80u) << 24;
    unsigned int em = byte & 0x7Fu;
    float v;
    if (em >= 8u) v = __builtin_bit_cast(float, (em + 960u) << 20);
    else v = (float)em * 0.001953125f;
    return __builtin_bit_cast(float, __builtin_bit_cast(unsigned int, v) | s);
}
__device__ __forceinline__ unsigned char enc1(float a) {
#if __has_builtin(__builtin_amdgcn_cvt_pk_fp8_f32)
    unsigned int w = __builtin_amdgcn_cvt_pk_fp8_f32(a, a, 0u, false);
    return (unsigned char)(w & 0xff);
#else
    return sw_e4m3(a);
#endif
}
__device__ __forceinline__ unsigned int enc4(float a, float b, float c, float d) {
#if __has_builtin(__builtin_amdgcn_cvt_pk_fp8_f32)
    unsigned int w = 0;
    w = __builtin_amdgcn_cvt_pk_fp8_f32(a, b, w, false);
    w = __builtin_amdgcn_cvt_pk_fp8_f32(c, d, w, true);
    return w;
#else
    return (unsigned int)sw_e4m3(a) | ((unsigned int)sw_e4m3(b) << 8) |
           ((unsigned int)sw_e4m3(c) << 16) | ((unsigned int)sw_e4m3(d) << 24);
#endif
}
__device__ __forceinline__ void dec4(unsigned int w, float* o) {
#if __has_builtin(__builtin_amdgcn_cvt_pk_f32_fp8)
    f32x2 lo = __builtin_amdgcn_cvt_pk_f32_fp8(w, false);
    f32x2 hi = __builtin_amdgcn_cvt_pk_f32_fp8(w, true);
    o[0] = lo.x; o[1] = lo.y; o[2] = hi.x; o[3] = hi.y;
#else
    o[0] = sw_f_e4m3(w & 0xff); o[1] = sw_f_e4m3((w >> 8) & 0xff);
    o[2] = sw_f_e4m3((w >> 16) & 0xff); o[3] = sw_f_e4m3(w >> 24);
#endif
}

// ---------- small precompute kernels ----------
__global__ void f32_to_bf16_x4(const float4* __restrict__ in, ushort4* __restrict__ out, int n4) {
    int i = blockIdx.x * 256 + threadIdx.x;
    if (i < n4) {
        float4 v = in[i];
        ushort4 o;
        o.x = f2b(v.x); o.y = f2b(v.y); o.z = f2b(v.z); o.w = f2b(v.w);
        out[i] = o;
    }
}

__global__ void f32_to_fp8_x4(const float4* __restrict__ in, unsigned int* __restrict__ out, int n4) {
    int i = blockIdx.x * 256 + threadIdx.x;
    if (i < n4) {
        float4 v = in[i];
        out[i] = enc4(v.x, v.y, v.z, v.w);
    }
}

__global__ void cvt_gather(const float* __restrict__ src, int src_ld, int coff,
                           unsigned short* __restrict__ dst, int perm) {
    int i = blockIdx.x * 256 + threadIdx.x;
    int r = i >> 8;
    int c = (i & 255) * 4;
    int sr = perm ? (((r & 3) << 10) + (r >> 2)) : r;
    float4 v = *reinterpret_cast<const float4*>(src + (size_t)sr * src_ld + coff + c);
    ushort4 o;
    o.x = f2b(v.x); o.y = f2b(v.y); o.z = f2b(v.z); o.w = f2b(v.w);
    *reinterpret_cast<ushort4*>(dst + (size_t)r * 1024 + c) = o;
}

__global__ void build_toks(const int* __restrict__ target, int* __restrict__ toks) {
    int idx = blockIdx.x * 256 + threadIdx.x;
    if (idx < T_ * B_) {
        int t = idx / B_, b = idx % B_;
        toks[idx] = (t == 0) ? 0 : target[b * T_ + t - 1];
    }
}

__global__ void build_bsum(const float* __restrict__ b_ih, const float* __restrict__ b_hh,
                           float* __restrict__ bsum) {
    int j = blockIdx.x * 256 + threadIdx.x;
    if (j < G4) {
        int pj = ((j & 3) << 10) + (j >> 2);
        bsum[j] = b_ih[pj] + b_hh[pj];
    }
}

// ---------- 64x64-tile bf16 MFMA GEMM (precompute only), BK=128, depth-2 counted vmcnt ----------
// MODE 0: f32 out + bias. MODE 1: fp8 byte out + bias (keys_proj).
template<int MODE>
__global__ __launch_bounds__(256) void gemm_mf(
    const unsigned short* __restrict__ A,
    const unsigned short* __restrict__ Bw,
    int K, int ldb, int ldc,
    float* __restrict__ C, unsigned char* __restrict__ C8,
    const float* __restrict__ bias)
{
    __shared__ unsigned short As[2 * 8192];
    __shared__ unsigned short Bs[2 * 8192];
    const int tid = threadIdx.x;
    const int lane = tid & 63;
    const int wv = tid >> 6;
    const int m0 = blockIdx.x * 64;
    const int n0 = blockIdx.y * 64;

    const unsigned short* ga[4];
    const unsigned short* gb[4];
    #pragma unroll
    for (int j = 0; j < 4; ++j) {
        int ci = tid + 256 * j;
        int row = ci >> 4;
        int src = (ci & 15) ^ (row & 7);
        ga[j] = A + (size_t)(m0 + row) * K + src * 8;
        gb[j] = Bw + (size_t)(n0 + row) * ldb + src * 8;
    }

    f32x4 acc[2][2] = {};
    const int r0 = (wv >> 1) * 32;
    const int cq0 = (wv & 1) * 32;
    const int fr = lane & 15;
    const int kg = lane >> 4;

    auto stage = [&](int k0, int p) {
        #pragma unroll
        for (int j = 0; j < 4; ++j) {
            gll16(ga[j] + k0, As + p * 8192 + j * 2048 + wv * 512);
            gll16(gb[j] + k0, Bs + p * 8192 + j * 2048 + wv * 512);
        }
    };

    stage(0, 0);
    stage(128, 1);
    int p = 0;
    for (int k0 = 0; k0 < K; k0 += 128) {
        if (k0 + 128 < K) {
            asm volatile("s_waitcnt vmcnt(8)" ::: "memory");
        } else {
            asm volatile("s_waitcnt vmcnt(0)" ::: "memory");
        }
        __builtin_amdgcn_sched_barrier(0);
        __builtin_amdgcn_s_barrier();
        __builtin_amdgcn_sched_barrier(0);
        const unsigned short* Ab = As + p * 8192;
        const unsigned short* Bb = Bs + p * 8192;
        bf16x8 af[2][4], bfr[2][4];
        #pragma unroll
        for (int f = 0; f < 2; ++f)
            #pragma unroll
            for (int kh = 0; kh < 4; ++kh) {
                int ra = r0 + f * 16 + fr;
                af[f][kh] = *(const bf16x8*)&Ab[ra * 128 + (((kh * 4 + kg) ^ (ra & 7)) << 3)];
                int rb = cq0 + f * 16 + fr;
                bfr[f][kh] = *(const bf16x8*)&Bb[rb * 128 + (((kh * 4 + kg) ^ (rb & 7)) << 3)];
            }
        asm volatile("s_waitcnt lgkmcnt(0)" ::: "memory");
        __builtin_amdgcn_sched_barrier(0);
        __builtin_amdgcn_s_barrier();
        __builtin_amdgcn_sched_barrier(0);
        if (k0 + 256 < K) stage(k0 + 256, p);
        __builtin_amdgcn_s_setprio(1);
        #pragma unroll
        for (int f = 0; f < 2; ++f)
            #pragma unroll
            for (int g = 0; g < 2; ++g)
                #pragma unroll
                for (int kh = 0; kh < 4; ++kh)
                    acc[f][g] = __builtin_amdgcn_mfma_f32_16x16x32_bf16(
                        af[f][kh], bfr[g][kh], acc[f][g], 0, 0, 0);
        __builtin_amdgcn_s_setprio(0);
        p ^= 1;
    }

    const int erow = (lane >> 4) * 4;
    const int ecol = lane & 15;
    #pragma unroll
    for (int f = 0; f < 2; ++f) {
        #pragma unroll
        for (int g = 0; g < 2; ++g) {
            #pragma unroll
            for (int r = 0; r < 4; ++r) {
                int row = m0 + r0 + f * 16 + erow + r;
                int col = n0 + cq0 + g * 16 + ecol;
                float v = acc[f][g][r] + bias[col];
                if (MODE == 0) C[(size_t)row * ldc + col] = v;
                else C8[(size_t)row * ldc + col] = enc1(v);
            }
        }
    }
}

// ---------- 64x32-tile bf16 MFMA GEMM, BK=128, depth-3 ----------
// MODE 0: C = v + bias[col] (ldc)
// MODE 2: col<1024 -> Cq=q(+bias); else gates(+Pemb[tok])
// MODE 4: gates-acc + fused LSTM pointwise epilogue (Cb = h out bf16)
template<int MODE>
__global__ __launch_bounds__(256) void gemm_n32(
    const unsigned short* __restrict__ A,
    const unsigned short* __restrict__ Bw,
    int K, int ldb, int ldc,
    float* __restrict__ C, unsigned short* __restrict__ Cb,
    const float* __restrict__ bias,
    const float* __restrict__ Pemb,
    const int* __restrict__ toks,
    float* __restrict__ Cq,
    float* __restrict__ Lg,
    int flag)
{
    __shared__ unsigned short As[3 * 8192];
    __shared__ unsigned short Bs[3 * 4096];
    const int tid = threadIdx.x;
    const int lane = tid & 63;
    const int wv = tid >> 6;
    const int m0 = blockIdx.x * 64;
    const int n0 = blockIdx.y * 32;

    const unsigned short* ga[4];
    const unsigned short* gb[2];
    #pragma unroll
    for (int j = 0; j < 4; ++j) {
        int ci = tid + 256 * j;
        int row = ci >> 4;
        int src = (ci & 15) ^ (row & 7);
        ga[j] = A + (size_t)(m0 + row) * K + src * 8;
    }
    #pragma unroll
    for (int j = 0; j < 2; ++j) {
        int ci = tid + 256 * j;
        int row = ci >> 4;
        int src = (ci & 15) ^ (row & 7);
        gb[j] = Bw + (size_t)(n0 + row) * ldb + src * 8;
    }

    f32x4 acc[2] = {};
    const int r0 = (wv >> 1) * 32;
    const int c0 = (wv & 1) * 16;
    const int fr = lane & 15;
    const int kg = lane >> 4;

    auto stage = [&](int k0, int p) {
        #pragma unroll
        for (int j = 0; j < 4; ++j)
            gll16(ga[j] + k0, As + p * 8192 + j * 2048 + wv * 512);
        #pragma unroll
        for (int j = 0; j < 2; ++j)
            gll16(gb[j] + k0, Bs + p * 4096 + j * 2048 + wv * 512);
    };

    stage(0, 0);
    stage(128, 1);
    stage(256, 2);
    int p = 0;
    for (int k0 = 0; k0 < K; k0 += 128) {
        if (k0 + 256 < K) {
            asm volatile("s_waitcnt vmcnt(12)" ::: "memory");
        } else if (k0 + 128 < K) {
            asm volatile("s_waitcnt vmcnt(6)" ::: "memory");
        } else {
            asm volatile("s_waitcnt vmcnt(0)" ::: "memory");
        }
        __builtin_amdgcn_sched_barrier(0);
        __builtin_amdgcn_s_barrier();
        __builtin_amdgcn_sched_barrier(0);
        const unsigned short* Ab = As + p * 8192;
        const unsigned short* Bb = Bs + p * 4096;
        bf16x8 af[2][4], bfr[4];
        #pragma unroll
        for (int kh = 0; kh < 4; ++kh) {
            #pragma unroll
            for (int f = 0; f < 2; ++f) {
                int ra = r0 + f * 16 + fr;
                af[f][kh] = *(const bf16x8*)&Ab[ra * 128 + (((kh * 4 + kg) ^ (ra & 7)) << 3)];
            }
            int rb = c0 + fr;
            bfr[kh] = *(const bf16x8*)&Bb[rb * 128 + (((kh * 4 + kg) ^ (rb & 7)) << 3)];
        }
        asm volatile("s_waitcnt lgkmcnt(0)" ::: "memory");
        __builtin_amdgcn_sched_barrier(0);
        __builtin_amdgcn_s_barrier();
        __builtin_amdgcn_sched_barrier(0);
        if (k0 + 384 < K) stage(k0 + 384, p);
        __builtin_amdgcn_s_setprio(1);
        #pragma unroll
        for (int f = 0; f < 2; ++f)
            #pragma unroll
            for (int kh = 0; kh < 4; ++kh)
                acc[f] = __builtin_amdgcn_mfma_f32_16x16x32_bf16(
                    af[f][kh], bfr[kh], acc[f], 0, 0, 0);
        __builtin_amdgcn_s_setprio(0);
        p = (p == 2) ? 0 : p + 1;
    }

    const int erow = (lane >> 4) * 4;
    const int ecol = lane & 15;

    if constexpr (MODE == 4) {
        __shared__ float Lt[64 * 32];
        __syncthreads();
        #pragma unroll
        for (int f = 0; f < 2; ++f)
            #pragma unroll
            for (int r = 0; r < 4; ++r)
                Lt[(r0 + f * 16 + erow + r) * 32 + c0 + ecol] = acc[f][r];
        __syncthreads();
        #pragma unroll
        for (int i = 0; i < 2; ++i) {
            int pi = tid + 256 * i;
            int r = pi >> 3, u = pi & 7;
            int b = m0 + r;
            int hh = (n0 >> 2) + u;
            f32x4 gv = *reinterpret_cast<const f32x4*>(&Lt[r * 32 + u * 4]);
            const float* gp = C + (size_t)b * G4 + n0 + u * 4;
            float iv = gv[0] + gp[0];
            float fv = gv[1] + gp[1];
            float gg = gv[2] + gp[2];
            float ov = gv[3] + gp[3];
            int ci = b * H_ + hh;
            float cn = fsigm(fv) * Cq[ci] + fsigm(iv) * ftanh(gg);
            float hn = fsigm(ov) * ftanh(cn);
            Cq[ci] = cn;
            Cb[ci] = f2b(hn);
            if (flag) Lg[ci] = hn;
        }
    } else {
        #pragma unroll
        for (int f = 0; f < 2; ++f) {
            #pragma unroll
            for (int r = 0; r < 4; ++r) {
                int row = m0 + r0 + f * 16 + erow + r;
                int col = n0 + c0 + ecol;
                float v = acc[f][r];
                if (MODE == 0) {
                    C[(size_t)row * ldc + col] = v + bias[col];
                } else {  // MODE 2: q | gates
                    if (col < H_) {
                        Cq[(size_t)row * H_ + col] = v + bias[col];
                    } else {
                        int cg = col - H_;
                        C[(size_t)row * G4 + cg] = v + Pemb[(size_t)toks[row] * G4 + cg];
                    }
                }
            }
        }
    }
}

// ---------- FUSED attention: energies + softmax + attn store + ctx half ----------
// grid 256 = (b, hh) pairs; 512 threads. Each block computes ALL 256 energies for
// its b (redundant across the hh pair -- no cross-block comm), then its 512-col
// half of ctx directly in f32. No pctx/es_g round trip, no combine launch.
__global__ __launch_bounds__(512) void attn_fused(
    const unsigned int* __restrict__ kp8,    // [B*S][256 words] fp8
    const float* __restrict__ q,             // [B][H]
    const float* __restrict__ Va,            // [H]
    const unsigned int* __restrict__ encb8,  // [B*S][256 words] fp8
    unsigned short* __restrict__ ctxb,       // [B][H] bf16
    float* __restrict__ attnOut,             // [B,T,S]
    int t)
{
    const int b = blockIdx.x >> 1;
    const int hh = blockIdx.x & 1;
    const int tid = threadIdx.x;
    const int lane = tid & 63;
    const int wv = tid >> 6;                 // 0..7
    __shared__ float qs[H_];
    __shared__ float vas[H_];
    __shared__ float es[S_];
    __shared__ float red[8];
    __shared__ float part[4][128][4];

    *reinterpret_cast<float2*>(&qs[tid * 2]) =
        *reinterpret_cast<const float2*>(&q[(size_t)b * H_ + tid * 2]);
    *reinterpret_cast<float2*>(&vas[tid * 2]) =
        *reinterpret_cast<const float2*>(&Va[tid * 2]);
    __syncthreads();

    // ---- energies: wave wv handles s = wv*32 + 0..31; lane covers h = lane*16..+15 ----
    for (int si = 0; si < 32; ++si) {
        int s = wv * 32 + si;
        uint4 u = reinterpret_cast<const uint4*>(
            kp8 + (size_t)(b * S_ + s) * 256)[lane];
        const int h0 = lane * 16;
        float d[4];
        float acc = 0.f;
        dec4(u.x, d);
        acc += vas[h0 + 0] * ftanh(qs[h0 + 0] + d[0]);
        acc += vas[h0 + 1] * ftanh(qs[h0 + 1] + d[1]);
        acc += vas[h0 + 2] * ftanh(qs[h0 + 2] + d[2]);
        acc += vas[h0 + 3] * ftanh(qs[h0 + 3] + d[3]);
        dec4(u.y, d);
        acc += vas[h0 + 4] * ftanh(qs[h0 + 4] + d[0]);
        acc += vas[h0 + 5] * ftanh(qs[h0 + 5] + d[1]);
        acc += vas[h0 + 6] * ftanh(qs[h0 + 6] + d[2]);
        acc += vas[h0 + 7] * ftanh(qs[h0 + 7] + d[3]);
        dec4(u.z, d);
        acc += vas[h0 + 8] * ftanh(qs[h0 + 8] + d[0]);
        acc += vas[h0 + 9] * ftanh(qs[h0 + 9] + d[1]);
        acc += vas[h0 + 10] * ftanh(qs[h0 + 10] + d[2]);
        acc += vas[h0 + 11] * ftanh(qs[h0 + 11] + d[3]);
        dec4(u.w, d);
        acc += vas[h0 + 12] * ftanh(qs[h0 + 12] + d[0]);
        acc += vas[h0 + 13] * ftanh(qs[h0 + 13] + d[1]);
        acc += vas[h0 + 14] * ftanh(qs[h0 + 14] + d[2]);
        acc += vas[h0 + 15] * ftanh(qs[h0 + 15] + d[3]);
        #pragma unroll
        for (int off = 32; off; off >>= 1) acc += __shfl_down(acc, off);
        if (lane == 0) es[s] = acc;
    }
    __syncthreads();

    // ---- raw-exp softmax over S=256 (energies bounded; overflow-safe) ----
    float ex = (tid < S_) ? __expf(es[tid]) : 0.f;
    float sm = ex;
    #pragma unroll
    for (int off = 32; off; off >>= 1) sm += __shfl_xor(sm, off);
    if (lane == 0) red[wv] = sm;
    __syncthreads();
    sm = 0.f;
    #pragma unroll
    for (int i = 0; i < 8; ++i) sm += red[i];
    float rZ = __builtin_amdgcn_rcpf(sm);
    if (tid < S_) {
        es[tid] = ex;                        // unnormalized weight for ctx
        if (hh == 0) attnOut[((size_t)(b * T_ + t)) * S_ + tid] = ex * rZ;
    }
    __syncthreads();

    // ---- ctx half: word w (4 cols), s-quarter sq; f32 accumulate ----
    const int w = tid & 127;                 // word within this half
    const int sq = tid >> 7;                 // 0..3
    const int gw = hh * 128 + w;             // global word index (of 256)
    float a0 = 0.f, a1 = 0.f, a2 = 0.f, a3 = 0.f;
    const unsigned int* ep = encb8 + (size_t)(b * S_ + sq * 64) * 256 + gw;
    #pragma unroll 4
    for (int s = 0; s < 64; ++s) {
        unsigned int u = ep[(size_t)s * 256];
        float d[4];
        dec4(u, d);
        float wt = es[sq * 64 + s];
        a0 += wt * d[0];
        a1 += wt * d[1];
        a2 += wt * d[2];
        a3 += wt * d[3];
    }
    part[sq][w][0] = a0; part[sq][w][1] = a1; part[sq][w][2] = a2; part[sq][w][3] = a3;
    __syncthreads();
    if (tid < 128) {
        f32x4 c4 = *reinterpret_cast<const f32x4*>(part[0][tid]);
        #pragma unroll
        for (int qd = 1; qd < 4; ++qd) {
            f32x4 pv = *reinterpret_cast<const f32x4*>(part[qd][tid]);
            c4[0] += pv[0]; c4[1] += pv[1]; c4[2] += pv[2]; c4[3] += pv[3];
        }
        ushort4 o;
        o.x = f2b(c4[0] * rZ); o.y = f2b(c4[1] * rZ);
        o.z = f2b(c4[2] * rZ); o.w = f2b(c4[3] * rZ);
        *reinterpret_cast<ushort4*>(&ctxb[(size_t)b * H_ + hh * 512 + tid * 4]) = o;
    }
}

// ---------- batched log-softmax over all (t,b) rows ----------
__global__ __launch_bounds__(256) void lsm_all(
    const float* __restrict__ lgall,   // [(t*B+b)][V]
    float* __restrict__ lp)            // [B,T,V]
{
    int r = blockIdx.x;
    int t = r >> 7, b = r & (B_ - 1);
    int tid = threadIdx.x;
    int lane = tid & 63, wv = tid >> 6;
    __shared__ float red[4];
    float a0 = lgall[(size_t)r * V_ + tid];
    float a1 = lgall[(size_t)r * V_ + 256 + tid];
    float mx = fmaxf(a0, a1);
    #pragma unroll
    for (int off = 32; off; off >>= 1) mx = fmaxf(mx, __shfl_xor(mx, off));
    if (lane == 0) red[wv] = mx;
    __syncthreads();
    mx = fmaxf(fmaxf(red[0], red[1]), fmaxf(red[2], red[3]));
    float sm = __expf(a0 - mx) + __expf(a1 - mx);
    #pragma unroll
    for (int off = 32; off; off >>= 1) sm += __shfl_xor(sm, off);
    __syncthreads();
    if (lane == 0) red[wv] = sm;
    __syncthreads();
    sm = red[0] + red[1] + red[2] + red[3];
    float lse = mx + __logf(sm);
    size_t off = ((size_t)b * T_ + t) * V_;
    lp[off + tid] = a0 - lse;
    lp[off + tid + 256] = a1 - lse;
}

// ---------- launch ----------
extern "C" void kernel_launch(void* const* d_in, const int* in_sizes, int n_in,
                              void* d_out, int out_size, void* d_ws, size_t ws_size,
                              hipStream_t stream) {
    const float* enc   = (const float*)d_in[0];
    const float* h0    = (const float*)d_in[1];
    const float* c0    = (const float*)d_in[2];
    const int*   targ  = (const int*)d_in[3];
    const float* emb   = (const float*)d_in[5];
    const float* Wa_w  = (const float*)d_in[6];
    const float* Wa_b  = (const float*)d_in[7];
    const float* Ua_w  = (const float*)d_in[8];
    const float* Ua_b  = (const float*)d_in[9];
    const float* Va_w  = (const float*)d_in[10];
    const float* W_ih  = (const float*)d_in[12];
    const float* W_hh  = (const float*)d_in[13];
    const float* b_ih  = (const float*)d_in[14];
    const float* b_hh  = (const float*)d_in[15];
    const float* out_w = (const float*)d_in[16];
    const float* out_b = (const float*)d_in[17];

    float* out  = (float*)d_out;
    float* lp   = out;                          // [B,T,V]
    float* hid  = out + (size_t)B_ * T_ * V_;   // [1,B,H]
    float* attn = hid + (size_t)B_ * H_;        // [B,T,S]

    char* w = (char*)d_ws;
    auto alloc = [&](size_t bytes) {
        char* p = w;
        w += (bytes + 255) & ~(size_t)255;
        return p;
    };
    const size_t NKP = (size_t)B_ * S_ * H_;
    unsigned int* kp8      = (unsigned int*)alloc(NKP);
    unsigned int* encb8    = (unsigned int*)alloc(NKP);
    char* uni = alloc(NKP * 2);   // encb (precompute) -> reused as hall + lgall
    unsigned short* encb = (unsigned short*)uni;
    unsigned short* hall = (unsigned short*)uni;
    float* lgall = (float*)(uni + (size_t)T_ * B_ * H_ * 2);
    unsigned short* Wcat_b = (unsigned short*)alloc((size_t)5120 * H_ * 2); // [Wa; W_hh(perm)]
    unsigned short* Wih1_b = (unsigned short*)alloc((size_t)G4 * H_ * 2);
    unsigned short* Wih2_b = (unsigned short*)alloc((size_t)G4 * H_ * 2);
    unsigned short* Uaw_b  = (unsigned short*)alloc((size_t)H_ * H_ * 2);
    unsigned short* emb_b  = (unsigned short*)alloc((size_t)V_ * H_ * 2);
    unsigned short* owb_b  = (unsigned short*)alloc((size_t)V_ * H_ * 2);
    unsigned short* hb0    = (unsigned short*)alloc((size_t)B_ * H_ * 2);
    unsigned short* ctxb   = (unsigned short*)alloc((size_t)B_ * H_ * 2);
    float* Pemb  = (float*)alloc((size_t)V_ * G4 * 4);
    float* bsumP = (float*)alloc((size_t)G4 * 4);
    int*   toks  = (int*)alloc((size_t)T_ * B_ * 4);
    float* cbuf  = (float*)alloc((size_t)B_ * H_ * 4);
    float* qbuf  = (float*)alloc((size_t)B_ * H_ * 4);
    float* gates = (float*)alloc((size_t)B_ * G4 * 4);
    if ((size_t)(w - (char*)d_ws) > ws_size) return;

    auto cvt = [&](const float* src, unsigned short* dst, size_t n) {
        int n4 = (int)(n / 4);
        f32_to_bf16_x4<<<(n4 + 255) / 256, 256, 0, stream>>>((const float4*)src, (ushort4*)dst, n4);
    };

    // precompute
    cvt(enc, encb, NKP);
    f32_to_fp8_x4<<<(int)(NKP / 4 + 255) / 256, 256, 0, stream>>>(
        (const float4*)enc, encb8, (int)(NKP / 4));
    cvt(Ua_w, Uaw_b, (size_t)H_ * H_);
    cvt(emb, emb_b, (size_t)V_ * H_);
    cvt(h0, hb0, (size_t)B_ * H_);
    cvt_gather<<<1024, 256, 0, stream>>>(Wa_w, H_, 0, Wcat_b, 0);
    cvt_gather<<<4096, 256, 0, stream>>>(W_hh, H_, 0, Wcat_b + (size_t)1024 * H_, 1);
    cvt_gather<<<512, 256, 0, stream>>>(out_w, H_, 0, owb_b, 0);
    cvt_gather<<<4096, 256, 0, stream>>>(W_ih, 2 * H_, 0, Wih1_b, 1);
    cvt_gather<<<4096, 256, 0, stream>>>(W_ih, 2 * H_, H_, Wih2_b, 1);
    build_toks<<<(T_ * B_ + 255) / 256, 256, 0, stream>>>(targ, toks);
    build_bsum<<<(G4 + 255) / 256, 256, 0, stream>>>(b_ih, b_hh, bsumP);
    hipMemcpyAsync(cbuf, c0, (size_t)B_ * H_ * 4, hipMemcpyDeviceToDevice, stream);

    // keys_proj: kp8 = fp8(encb @ Ua_w^T + Ua_b)
    gemm_mf<1><<<dim3((B_ * S_) / 64, H_ / 64), 256, 0, stream>>>(
        encb, Uaw_b, H_, H_, H_, nullptr, (unsigned char*)kp8, Ua_b);
    // Pemb (permuted): emb @ W_ih[:, :H](perm)^T + bsumP
    gemm_mf<0><<<dim3(V_ / 64, G4 / 64), 256, 0, stream>>>(
        emb_b, Wih1_b, H_, H_, G4, Pemb, nullptr, bsumP);

    // sequential decode: 3 launches per step (logits deferred; attn fused)
    for (int t = 0; t < T_; ++t) {
        const unsigned short* hprev = (t == 0) ? hb0 : hall + (size_t)(t - 1) * B_ * H_;
        gemm_n32<2><<<dim3(2, 160), 256, 0, stream>>>(
            hprev, Wcat_b, H_, H_, 0, gates, nullptr, Wa_b,
            Pemb, toks + t * B_, qbuf, nullptr, 0);
        attn_fused<<<256, 512, 0, stream>>>(kp8, qbuf, Va_w, encb8, ctxb, attn, t);
        gemm_n32<4><<<dim3(2, 128), 256, 0, stream>>>(
            ctxb, Wih2_b, H_, H_, 0, gates, hall + (size_t)t * B_ * H_, nullptr,
            nullptr, nullptr, cbuf, hid, t == T_ - 1);
    }

    // batched logits over all steps + log-softmax
    gemm_n32<0><<<dim3((T_ * B_) / 64, V_ / 32), 256, 0, stream>>>(
        hall, owb_b, H_, H_, V_, lgall, nullptr, out_b,
        nullptr, nullptr, nullptr, nullptr, 0);
    lsm_all<<<T_ * B_, 256, 0, stream>>>(lgall, lp);
}

// Round 15
// 5567.390 us; speedup vs baseline: 6.7817x; 1.3619x over previous
//
#include <hip/hip_runtime.h>

#define B_ 128
#define S_ 256
#define H_ 1024
#define V_ 512
#define T_ 128
#define G4 4096

typedef __attribute__((ext_vector_type(8))) short bf16x8;
typedef __attribute__((ext_vector_type(4))) float f32x4;
typedef __attribute__((ext_vector_type(2))) float f32x2;

// ---------- helpers ----------
__device__ __forceinline__ float bf2f(unsigned short x) {
    unsigned int u = ((unsigned int)x) << 16;
    return __builtin_bit_cast(float, u);
}
__device__ __forceinline__ unsigned short f2b(float f) {
    unsigned int u = __builtin_bit_cast(unsigned int, f);
    u = u + 0x7fffu + ((u >> 16) & 1u);
    return (unsigned short)(u >> 16);
}
__device__ __forceinline__ float ftanh(float x) {
    float e = __expf(2.f * x);
    return 1.f - 2.f * __builtin_amdgcn_rcpf(e + 1.f);
}
__device__ __forceinline__ float fsigm(float x) {
    return __builtin_amdgcn_rcpf(1.f + __expf(-x));
}
__device__ __forceinline__ void gll16(const void* g, void* l) {
    __builtin_amdgcn_global_load_lds(
        (const __attribute__((address_space(1))) unsigned int*)g,
        (__attribute__((address_space(3))) unsigned int*)l, 16, 0, 0);
}

// ---------- fp8 e4m3fn (OCP) helpers ----------
__device__ __forceinline__ unsigned char sw_e4m3(float f) {
    unsigned int ub = __builtin_bit_cast(unsigned int, f);
    unsigned char s = (unsigned char)((ub >> 24) & 0x80);
    float a = fabsf(f);
    if (!(a < 464.f)) return (unsigned char)(s | 0x7E);
    if (a < 0.0009765625f) return s;
    if (a < 0.015625f) {
        int m = (int)(a * 512.f + 0.5f);
        if (m >= 8) return (unsigned char)(s | 0x08);
        return (unsigned char)(s | m);
    }
    unsigned int u = __builtin_bit_cast(unsigned int, a);
    u += 0x7FFFF + ((u >> 20) & 1);
    int e = (int)(u >> 23) - 127;
    if (e > 8) return (unsigned char)(s | 0x7E);
    unsigned int man = (u >> 20) & 7;
    return (unsigned char)(s | ((unsigned int)(e + 7) << 3) | man);
}
__device__ __forceinline__ float sw_f_e4m3(unsigned int byte) {
    unsigned int s = (byte & 0x80u) << 24;
    unsigned int em = byte & 0x7Fu;
    float v;
    if (em >= 8u) v = __builtin_bit_cast(float, (em + 960u) << 20);
    else v = (float)em * 0.001953125f;
    return __builtin_bit_cast(float, __builtin_bit_cast(unsigned int, v) | s);
}
__device__ __forceinline__ unsigned char enc1(float a) {
#if __has_builtin(__builtin_amdgcn_cvt_pk_fp8_f32)
    unsigned int w = __builtin_amdgcn_cvt_pk_fp8_f32(a, a, 0u, false);
    return (unsigned char)(w & 0xff);
#else
    return sw_e4m3(a);
#endif
}
__device__ __forceinline__ unsigned int enc4(float a, float b, float c, float d) {
#if __has_builtin(__builtin_amdgcn_cvt_pk_fp8_f32)
    unsigned int w = 0;
    w = __builtin_amdgcn_cvt_pk_fp8_f32(a, b, w, false);
    w = __builtin_amdgcn_cvt_pk_fp8_f32(c, d, w, true);
    return w;
#else
    return (unsigned int)sw_e4m3(a) | ((unsigned int)sw_e4m3(b) << 8) |
           ((unsigned int)sw_e4m3(c) << 16) | ((unsigned int)sw_e4m3(d) << 24);
#endif
}
__device__ __forceinline__ void dec4(unsigned int w, float* o) {
#if __has_builtin(__builtin_amdgcn_cvt_pk_f32_fp8)
    f32x2 lo = __builtin_amdgcn_cvt_pk_f32_fp8(w, false);
    f32x2 hi = __builtin_amdgcn_cvt_pk_f32_fp8(w, true);
    o[0] = lo.x; o[1] = lo.y; o[2] = hi.x; o[3] = hi.y;
#else
    o[0] = sw_f_e4m3(w & 0xff); o[1] = sw_f_e4m3((w >> 8) & 0xff);
    o[2] = sw_f_e4m3((w >> 16) & 0xff); o[3] = sw_f_e4m3(w >> 24);
#endif
}

// ---------- small precompute kernels ----------
__global__ void f32_to_bf16_x4(const float4* __restrict__ in, ushort4* __restrict__ out, int n4) {
    int i = blockIdx.x * 256 + threadIdx.x;
    if (i < n4) {
        float4 v = in[i];
        ushort4 o;
        o.x = f2b(v.x); o.y = f2b(v.y); o.z = f2b(v.z); o.w = f2b(v.w);
        out[i] = o;
    }
}

__global__ void f32_to_fp8_x4(const float4* __restrict__ in, unsigned int* __restrict__ out, int n4) {
    int i = blockIdx.x * 256 + threadIdx.x;
    if (i < n4) {
        float4 v = in[i];
        out[i] = enc4(v.x, v.y, v.z, v.w);
    }
}

__global__ void cvt_gather(const float* __restrict__ src, int src_ld, int coff,
                           unsigned short* __restrict__ dst, int perm) {
    int i = blockIdx.x * 256 + threadIdx.x;
    int r = i >> 8;
    int c = (i & 255) * 4;
    int sr = perm ? (((r & 3) << 10) + (r >> 2)) : r;
    float4 v = *reinterpret_cast<const float4*>(src + (size_t)sr * src_ld + coff + c);
    ushort4 o;
    o.x = f2b(v.x); o.y = f2b(v.y); o.z = f2b(v.z); o.w = f2b(v.w);
    *reinterpret_cast<ushort4*>(dst + (size_t)r * 1024 + c) = o;
}

__global__ void build_toks(const int* __restrict__ target, int* __restrict__ toks) {
    int idx = blockIdx.x * 256 + threadIdx.x;
    if (idx < T_ * B_) {
        int t = idx / B_, b = idx % B_;
        toks[idx] = (t == 0) ? 0 : target[b * T_ + t - 1];
    }
}

__global__ void build_bsum(const float* __restrict__ b_ih, const float* __restrict__ b_hh,
                           float* __restrict__ bsum) {
    int j = blockIdx.x * 256 + threadIdx.x;
    if (j < G4) {
        int pj = ((j & 3) << 10) + (j >> 2);
        bsum[j] = b_ih[pj] + b_hh[pj];
    }
}

// ---------- 64x64-tile bf16 MFMA GEMM (precompute only), BK=128, depth-2 counted vmcnt ----------
// MODE 0: f32 out + bias. MODE 1: fp8 byte out + bias (keys_proj).
template<int MODE>
__global__ __launch_bounds__(256) void gemm_mf(
    const unsigned short* __restrict__ A,
    const unsigned short* __restrict__ Bw,
    int K, int ldb, int ldc,
    float* __restrict__ C, unsigned char* __restrict__ C8,
    const float* __restrict__ bias)
{
    __shared__ unsigned short As[2 * 8192];
    __shared__ unsigned short Bs[2 * 8192];
    const int tid = threadIdx.x;
    const int lane = tid & 63;
    const int wv = tid >> 6;
    const int m0 = blockIdx.x * 64;
    const int n0 = blockIdx.y * 64;

    const unsigned short* ga[4];
    const unsigned short* gb[4];
    #pragma unroll
    for (int j = 0; j < 4; ++j) {
        int ci = tid + 256 * j;
        int row = ci >> 4;
        int src = (ci & 15) ^ (row & 7);
        ga[j] = A + (size_t)(m0 + row) * K + src * 8;
        gb[j] = Bw + (size_t)(n0 + row) * ldb + src * 8;
    }

    f32x4 acc[2][2] = {};
    const int r0 = (wv >> 1) * 32;
    const int cq0 = (wv & 1) * 32;
    const int fr = lane & 15;
    const int kg = lane >> 4;

    auto stage = [&](int k0, int p) {
        #pragma unroll
        for (int j = 0; j < 4; ++j) {
            gll16(ga[j] + k0, As + p * 8192 + j * 2048 + wv * 512);
            gll16(gb[j] + k0, Bs + p * 8192 + j * 2048 + wv * 512);
        }
    };

    stage(0, 0);
    stage(128, 1);
    int p = 0;
    for (int k0 = 0; k0 < K; k0 += 128) {
        if (k0 + 128 < K) {
            asm volatile("s_waitcnt vmcnt(8)" ::: "memory");
        } else {
            asm volatile("s_waitcnt vmcnt(0)" ::: "memory");
        }
        __builtin_amdgcn_sched_barrier(0);
        __builtin_amdgcn_s_barrier();
        __builtin_amdgcn_sched_barrier(0);
        const unsigned short* Ab = As + p * 8192;
        const unsigned short* Bb = Bs + p * 8192;
        bf16x8 af[2][4], bfr[2][4];
        #pragma unroll
        for (int f = 0; f < 2; ++f)
            #pragma unroll
            for (int kh = 0; kh < 4; ++kh) {
                int ra = r0 + f * 16 + fr;
                af[f][kh] = *(const bf16x8*)&Ab[ra * 128 + (((kh * 4 + kg) ^ (ra & 7)) << 3)];
                int rb = cq0 + f * 16 + fr;
                bfr[f][kh] = *(const bf16x8*)&Bb[rb * 128 + (((kh * 4 + kg) ^ (rb & 7)) << 3)];
            }
        asm volatile("s_waitcnt lgkmcnt(0)" ::: "memory");
        __builtin_amdgcn_sched_barrier(0);
        __builtin_amdgcn_s_barrier();
        __builtin_amdgcn_sched_barrier(0);
        if (k0 + 256 < K) stage(k0 + 256, p);
        __builtin_amdgcn_s_setprio(1);
        #pragma unroll
        for (int f = 0; f < 2; ++f)
            #pragma unroll
            for (int g = 0; g < 2; ++g)
                #pragma unroll
                for (int kh = 0; kh < 4; ++kh)
                    acc[f][g] = __builtin_amdgcn_mfma_f32_16x16x32_bf16(
                        af[f][kh], bfr[g][kh], acc[f][g], 0, 0, 0);
        __builtin_amdgcn_s_setprio(0);
        p ^= 1;
    }

    const int erow = (lane >> 4) * 4;
    const int ecol = lane & 15;
    #pragma unroll
    for (int f = 0; f < 2; ++f) {
        #pragma unroll
        for (int g = 0; g < 2; ++g) {
            #pragma unroll
            for (int r = 0; r < 4; ++r) {
                int row = m0 + r0 + f * 16 + erow + r;
                int col = n0 + cq0 + g * 16 + ecol;
                float v = acc[f][g][r] + bias[col];
                if (MODE == 0) C[(size_t)row * ldc + col] = v;
                else C8[(size_t)row * ldc + col] = enc1(v);
            }
        }
    }
}

// ---------- 64x32-tile bf16 MFMA GEMM, BK=128, depth-3 ----------
// MODE 0: C = v + bias[col] (ldc)
// MODE 2: col<1024 -> Cq=q(+bias); else gates(+Pemb[tok])
// MODE 4: gates-acc + fused LSTM pointwise epilogue (Cb = h out bf16)
template<int MODE>
__global__ __launch_bounds__(256) void gemm_n32(
    const unsigned short* __restrict__ A,
    const unsigned short* __restrict__ Bw,
    int K, int ldb, int ldc,
    float* __restrict__ C, unsigned short* __restrict__ Cb,
    const float* __restrict__ bias,
    const float* __restrict__ Pemb,
    const int* __restrict__ toks,
    float* __restrict__ Cq,
    float* __restrict__ Lg,
    int flag)
{
    __shared__ unsigned short As[3 * 8192];
    __shared__ unsigned short Bs[3 * 4096];
    const int tid = threadIdx.x;
    const int lane = tid & 63;
    const int wv = tid >> 6;
    const int m0 = blockIdx.x * 64;
    const int n0 = blockIdx.y * 32;

    const unsigned short* ga[4];
    const unsigned short* gb[2];
    #pragma unroll
    for (int j = 0; j < 4; ++j) {
        int ci = tid + 256 * j;
        int row = ci >> 4;
        int src = (ci & 15) ^ (row & 7);
        ga[j] = A + (size_t)(m0 + row) * K + src * 8;
    }
    #pragma unroll
    for (int j = 0; j < 2; ++j) {
        int ci = tid + 256 * j;
        int row = ci >> 4;
        int src = (ci & 15) ^ (row & 7);
        gb[j] = Bw + (size_t)(n0 + row) * ldb + src * 8;
    }

    f32x4 acc[2] = {};
    const int r0 = (wv >> 1) * 32;
    const int c0 = (wv & 1) * 16;
    const int fr = lane & 15;
    const int kg = lane >> 4;

    auto stage = [&](int k0, int p) {
        #pragma unroll
        for (int j = 0; j < 4; ++j)
            gll16(ga[j] + k0, As + p * 8192 + j * 2048 + wv * 512);
        #pragma unroll
        for (int j = 0; j < 2; ++j)
            gll16(gb[j] + k0, Bs + p * 4096 + j * 2048 + wv * 512);
    };

    stage(0, 0);
    stage(128, 1);
    stage(256, 2);
    int p = 0;
    for (int k0 = 0; k0 < K; k0 += 128) {
        if (k0 + 256 < K) {
            asm volatile("s_waitcnt vmcnt(12)" ::: "memory");
        } else if (k0 + 128 < K) {
            asm volatile("s_waitcnt vmcnt(6)" ::: "memory");
        } else {
            asm volatile("s_waitcnt vmcnt(0)" ::: "memory");
        }
        __builtin_amdgcn_sched_barrier(0);
        __builtin_amdgcn_s_barrier();
        __builtin_amdgcn_sched_barrier(0);
        const unsigned short* Ab = As + p * 8192;
        const unsigned short* Bb = Bs + p * 4096;
        bf16x8 af[2][4], bfr[4];
        #pragma unroll
        for (int kh = 0; kh < 4; ++kh) {
            #pragma unroll
            for (int f = 0; f < 2; ++f) {
                int ra = r0 + f * 16 + fr;
                af[f][kh] = *(const bf16x8*)&Ab[ra * 128 + (((kh * 4 + kg) ^ (ra & 7)) << 3)];
            }
            int rb = c0 + fr;
            bfr[kh] = *(const bf16x8*)&Bb[rb * 128 + (((kh * 4 + kg) ^ (rb & 7)) << 3)];
        }
        asm volatile("s_waitcnt lgkmcnt(0)" ::: "memory");
        __builtin_amdgcn_sched_barrier(0);
        __builtin_amdgcn_s_barrier();
        __builtin_amdgcn_sched_barrier(0);
        if (k0 + 384 < K) stage(k0 + 384, p);
        __builtin_amdgcn_s_setprio(1);
        #pragma unroll
        for (int f = 0; f < 2; ++f)
            #pragma unroll
            for (int kh = 0; kh < 4; ++kh)
                acc[f] = __builtin_amdgcn_mfma_f32_16x16x32_bf16(
                    af[f][kh], bfr[kh], acc[f], 0, 0, 0);
        __builtin_amdgcn_s_setprio(0);
        p = (p == 2) ? 0 : p + 1;
    }

    const int erow = (lane >> 4) * 4;
    const int ecol = lane & 15;

    if constexpr (MODE == 4) {
        __shared__ float Lt[64 * 32];
        __syncthreads();
        #pragma unroll
        for (int f = 0; f < 2; ++f)
            #pragma unroll
            for (int r = 0; r < 4; ++r)
                Lt[(r0 + f * 16 + erow + r) * 32 + c0 + ecol] = acc[f][r];
        __syncthreads();
        #pragma unroll
        for (int i = 0; i < 2; ++i) {
            int pi = tid + 256 * i;
            int r = pi >> 3, u = pi & 7;
            int b = m0 + r;
            int hh = (n0 >> 2) + u;
            f32x4 gv = *reinterpret_cast<const f32x4*>(&Lt[r * 32 + u * 4]);
            const float* gp = C + (size_t)b * G4 + n0 + u * 4;
            float iv = gv[0] + gp[0];
            float fv = gv[1] + gp[1];
            float gg = gv[2] + gp[2];
            float ov = gv[3] + gp[3];
            int ci = b * H_ + hh;
            float cn = fsigm(fv) * Cq[ci] + fsigm(iv) * ftanh(gg);
            float hn = fsigm(ov) * ftanh(cn);
            Cq[ci] = cn;
            Cb[ci] = f2b(hn);
            if (flag) Lg[ci] = hn;
        }
    } else {
        #pragma unroll
        for (int f = 0; f < 2; ++f) {
            #pragma unroll
            for (int r = 0; r < 4; ++r) {
                int row = m0 + r0 + f * 16 + erow + r;
                int col = n0 + c0 + ecol;
                float v = acc[f][r];
                if (MODE == 0) {
                    C[(size_t)row * ldc + col] = v + bias[col];
                } else {  // MODE 2: q | gates
                    if (col < H_) {
                        Cq[(size_t)row * H_ + col] = v + bias[col];
                    } else {
                        int cg = col - H_;
                        C[(size_t)row * G4 + cg] = v + Pemb[(size_t)toks[row] * G4 + cg];
                    }
                }
            }
        }
    }
}

// ---------- attention energies + raw-exp partial context, grid (B,8) x 512 ----------
// Each block: 32 s-values (8 waves x 4 s, same per-wave chain depth as the proven
// (B,16)x256 version), q/Va staged once, pctx written as 8 chunks of H.
__global__ __launch_bounds__(512) void attn_e(
    const unsigned int* __restrict__ kp8,
    const float* __restrict__ q,
    const float* __restrict__ Va,
    const unsigned int* __restrict__ encb8,
    float* __restrict__ es_g,
    unsigned short* __restrict__ pctx)       // [B, 8, H] bf16
{
    const int b = blockIdx.x;
    const int sh = blockIdx.y;               // s-chunk of 32
    const int tid = threadIdx.x;
    const int lane = tid & 63;
    const int wv = tid >> 6;                 // 0..7
    __shared__ float qs[H_];
    __shared__ float vas[H_];
    __shared__ float pe[32];

    *reinterpret_cast<float2*>(&qs[tid * 2]) =
        *reinterpret_cast<const float2*>(&q[(size_t)b * H_ + tid * 2]);
    *reinterpret_cast<float2*>(&vas[tid * 2]) =
        *reinterpret_cast<const float2*>(&Va[tid * 2]);
    __syncthreads();

    // ---- energies: wave wv handles s_loc = wv*4 + 0..3; lane covers h = lane*16..+15 ----
    #pragma unroll
    for (int si = 0; si < 4; ++si) {
        int s_loc = wv * 4 + si;
        const uint4* kr = reinterpret_cast<const uint4*>(
            kp8 + (size_t)(b * S_ + sh * 32 + s_loc) * 256);
        uint4 u = kr[lane];
        const int h0 = lane * 16;
        float d[4];
        float acc = 0.f;
        dec4(u.x, d);
        acc += vas[h0 + 0] * ftanh(qs[h0 + 0] + d[0]);
        acc += vas[h0 + 1] * ftanh(qs[h0 + 1] + d[1]);
        acc += vas[h0 + 2] * ftanh(qs[h0 + 2] + d[2]);
        acc += vas[h0 + 3] * ftanh(qs[h0 + 3] + d[3]);
        dec4(u.y, d);
        acc += vas[h0 + 4] * ftanh(qs[h0 + 4] + d[0]);
        acc += vas[h0 + 5] * ftanh(qs[h0 + 5] + d[1]);
        acc += vas[h0 + 6] * ftanh(qs[h0 + 6] + d[2]);
        acc += vas[h0 + 7] * ftanh(qs[h0 + 7] + d[3]);
        dec4(u.z, d);
        acc += vas[h0 + 8] * ftanh(qs[h0 + 8] + d[0]);
        acc += vas[h0 + 9] * ftanh(qs[h0 + 9] + d[1]);
        acc += vas[h0 + 10] * ftanh(qs[h0 + 10] + d[2]);
        acc += vas[h0 + 11] * ftanh(qs[h0 + 11] + d[3]);
        dec4(u.w, d);
        acc += vas[h0 + 12] * ftanh(qs[h0 + 12] + d[0]);
        acc += vas[h0 + 13] * ftanh(qs[h0 + 13] + d[1]);
        acc += vas[h0 + 14] * ftanh(qs[h0 + 14] + d[2]);
        acc += vas[h0 + 15] * ftanh(qs[h0 + 15] + d[3]);
        #pragma unroll
        for (int off = 32; off; off >>= 1) acc += __shfl_down(acc, off);
        if (lane == 0) {
            pe[s_loc] = __expf(acc);
            es_g[(size_t)b * S_ + sh * 32 + s_loc] = acc;
        }
    }
    __syncthreads();

    // ---- raw-exp-weighted partial context over 32 s (fp8 in, bf16 out) ----
    // thread covers 2 cols via one u32 word? No: 512 threads x 2 cols = 1024 cols.
    const int wq = tid >> 8;                 // 0/1: s-half of the 32
    const int cw = tid & 255;                // word index (4 cols each)... see below
    // Each thread handles word (tid & 255) for s-half wq (16 s each); the two
    // halves are combined via LDS.
    __shared__ float ph[2][256][4];
    {
        float a0 = 0.f, a1 = 0.f, a2 = 0.f, a3 = 0.f;
        const unsigned int* ep = encb8 + (size_t)(b * S_ + sh * 32 + wq * 16) * 256 + cw;
        #pragma unroll
        for (int sl = 0; sl < 16; ++sl) {
            unsigned int u = ep[(size_t)sl * 256];
            float d[4];
            dec4(u, d);
            float wt = pe[wq * 16 + sl];
            a0 += wt * d[0];
            a1 += wt * d[1];
            a2 += wt * d[2];
            a3 += wt * d[3];
        }
        ph[wq][cw][0] = a0; ph[wq][cw][1] = a1; ph[wq][cw][2] = a2; ph[wq][cw][3] = a3;
    }
    __syncthreads();
    if (tid < 256) {
        float a0 = ph[0][tid][0] + ph[1][tid][0];
        float a1 = ph[0][tid][1] + ph[1][tid][1];
        float a2 = ph[0][tid][2] + ph[1][tid][2];
        float a3 = ph[0][tid][3] + ph[1][tid][3];
        ushort4 o4;
        o4.x = f2b(a0); o4.y = f2b(a1); o4.z = f2b(a2); o4.w = f2b(a3);
        *reinterpret_cast<ushort4*>(&pctx[((size_t)b * 8 + sh) * H_ + tid * 4]) = o4;
    }
}

// ---------- combine: Z-sum + attn-weight store + ctx finalize, grid (B,2) x 256 ----------
__global__ __launch_bounds__(256) void attn_comb(
    const float* __restrict__ es_g,
    const unsigned short* __restrict__ pctx, // [B, 8, H] bf16
    unsigned short* __restrict__ ctxb,
    float* __restrict__ attnOut,
    int t)
{
    const int b = blockIdx.x;
    const int hh = blockIdx.y;
    const int tid = threadIdx.x;
    const int lane = tid & 63;
    const int wv = tid >> 6;
    __shared__ float reds[4];

    float ex = __expf(es_g[(size_t)b * S_ + tid]);
    float sm = ex;
    #pragma unroll
    for (int off = 32; off; off >>= 1) sm += __shfl_xor(sm, off);
    if (lane == 0) reds[wv] = sm;
    __syncthreads();
    sm = reds[0] + reds[1] + reds[2] + reds[3];
    float rZ = __builtin_amdgcn_rcpf(sm);
    if (hh == 0) attnOut[((size_t)(b * T_ + t)) * S_ + tid] = ex * rZ;

    const int c0 = hh * 512 + tid * 2;
    float a0 = 0.f, a1 = 0.f;
    #pragma unroll
    for (int blk = 0; blk < 8; ++blk) {
        ushort2 pv = *reinterpret_cast<const ushort2*>(
            &pctx[((size_t)b * 8 + blk) * H_ + c0]);
        a0 += bf2f(pv.x); a1 += bf2f(pv.y);
    }
    ushort2 o; o.x = f2b(a0 * rZ); o.y = f2b(a1 * rZ);
    *reinterpret_cast<ushort2*>(&ctxb[(size_t)b * H_ + c0]) = o;
}

// ---------- batched log-softmax over all (t,b) rows ----------
__global__ __launch_bounds__(256) void lsm_all(
    const float* __restrict__ lgall,   // [(t*B+b)][V]
    float* __restrict__ lp)            // [B,T,V]
{
    int r = blockIdx.x;
    int t = r >> 7, b = r & (B_ - 1);
    int tid = threadIdx.x;
    int lane = tid & 63, wv = tid >> 6;
    __shared__ float red[4];
    float a0 = lgall[(size_t)r * V_ + tid];
    float a1 = lgall[(size_t)r * V_ + 256 + tid];
    float mx = fmaxf(a0, a1);
    #pragma unroll
    for (int off = 32; off; off >>= 1) mx = fmaxf(mx, __shfl_xor(mx, off));
    if (lane == 0) red[wv] = mx;
    __syncthreads();
    mx = fmaxf(fmaxf(red[0], red[1]), fmaxf(red[2], red[3]));
    float sm = __expf(a0 - mx) + __expf(a1 - mx);
    #pragma unroll
    for (int off = 32; off; off >>= 1) sm += __shfl_xor(sm, off);
    __syncthreads();
    if (lane == 0) red[wv] = sm;
    __syncthreads();
    sm = red[0] + red[1] + red[2] + red[3];
    float lse = mx + __logf(sm);
    size_t off = ((size_t)b * T_ + t) * V_;
    lp[off + tid] = a0 - lse;
    lp[off + tid + 256] = a1 - lse;
}

// ---------- launch ----------
extern "C" void kernel_launch(void* const* d_in, const int* in_sizes, int n_in,
                              void* d_out, int out_size, void* d_ws, size_t ws_size,
                              hipStream_t stream) {
    const float* enc   = (const float*)d_in[0];
    const float* h0    = (const float*)d_in[1];
    const float* c0    = (const float*)d_in[2];
    const int*   targ  = (const int*)d_in[3];
    const float* emb   = (const float*)d_in[5];
    const float* Wa_w  = (const float*)d_in[6];
    const float* Wa_b  = (const float*)d_in[7];
    const float* Ua_w  = (const float*)d_in[8];
    const float* Ua_b  = (const float*)d_in[9];
    const float* Va_w  = (const float*)d_in[10];
    const float* W_ih  = (const float*)d_in[12];
    const float* W_hh  = (const float*)d_in[13];
    const float* b_ih  = (const float*)d_in[14];
    const float* b_hh  = (const float*)d_in[15];
    const float* out_w = (const float*)d_in[16];
    const float* out_b = (const float*)d_in[17];

    float* out  = (float*)d_out;
    float* lp   = out;                          // [B,T,V]
    float* hid  = out + (size_t)B_ * T_ * V_;   // [1,B,H]
    float* attn = hid + (size_t)B_ * H_;        // [B,T,S]

    char* w = (char*)d_ws;
    auto alloc = [&](size_t bytes) {
        char* p = w;
        w += (bytes + 255) & ~(size_t)255;
        return p;
    };
    const size_t NKP = (size_t)B_ * S_ * H_;
    unsigned int* kp8      = (unsigned int*)alloc(NKP);
    unsigned int* encb8    = (unsigned int*)alloc(NKP);
    char* uni = alloc(NKP * 2);   // encb (precompute) -> reused as hall + lgall
    unsigned short* encb = (unsigned short*)uni;
    unsigned short* hall = (unsigned short*)uni;
    float* lgall = (float*)(uni + (size_t)T_ * B_ * H_ * 2);
    unsigned short* Wcat_b = (unsigned short*)alloc((size_t)5120 * H_ * 2); // [Wa; W_hh(perm)]
    unsigned short* Wih1_b = (unsigned short*)alloc((size_t)G4 * H_ * 2);
    unsigned short* Wih2_b = (unsigned short*)alloc((size_t)G4 * H_ * 2);
    unsigned short* Uaw_b  = (unsigned short*)alloc((size_t)H_ * H_ * 2);
    unsigned short* emb_b  = (unsigned short*)alloc((size_t)V_ * H_ * 2);
    unsigned short* owb_b  = (unsigned short*)alloc((size_t)V_ * H_ * 2);
    unsigned short* hb0    = (unsigned short*)alloc((size_t)B_ * H_ * 2);
    unsigned short* ctxb   = (unsigned short*)alloc((size_t)B_ * H_ * 2);
    float* Pemb  = (float*)alloc((size_t)V_ * G4 * 4);
    float* bsumP = (float*)alloc((size_t)G4 * 4);
    int*   toks  = (int*)alloc((size_t)T_ * B_ * 4);
    float* cbuf  = (float*)alloc((size_t)B_ * H_ * 4);
    float* qbuf  = (float*)alloc((size_t)B_ * H_ * 4);
    float* gates = (float*)alloc((size_t)B_ * G4 * 4);
    float* es_g  = (float*)alloc((size_t)B_ * S_ * 4);
    unsigned short* pctx = (unsigned short*)alloc((size_t)B_ * 8 * H_ * 2);
    if ((size_t)(w - (char*)d_ws) > ws_size) return;

    auto cvt = [&](const float* src, unsigned short* dst, size_t n) {
        int n4 = (int)(n / 4);
        f32_to_bf16_x4<<<(n4 + 255) / 256, 256, 0, stream>>>((const float4*)src, (ushort4*)dst, n4);
    };

    // precompute
    cvt(enc, encb, NKP);
    f32_to_fp8_x4<<<(int)(NKP / 4 + 255) / 256, 256, 0, stream>>>(
        (const float4*)enc, encb8, (int)(NKP / 4));
    cvt(Ua_w, Uaw_b, (size_t)H_ * H_);
    cvt(emb, emb_b, (size_t)V_ * H_);
    cvt(h0, hb0, (size_t)B_ * H_);
    cvt_gather<<<1024, 256, 0, stream>>>(Wa_w, H_, 0, Wcat_b, 0);
    cvt_gather<<<4096, 256, 0, stream>>>(W_hh, H_, 0, Wcat_b + (size_t)1024 * H_, 1);
    cvt_gather<<<512, 256, 0, stream>>>(out_w, H_, 0, owb_b, 0);
    cvt_gather<<<4096, 256, 0, stream>>>(W_ih, 2 * H_, 0, Wih1_b, 1);
    cvt_gather<<<4096, 256, 0, stream>>>(W_ih, 2 * H_, H_, Wih2_b, 1);
    build_toks<<<(T_ * B_ + 255) / 256, 256, 0, stream>>>(targ, toks);
    build_bsum<<<(G4 + 255) / 256, 256, 0, stream>>>(b_ih, b_hh, bsumP);
    hipMemcpyAsync(cbuf, c0, (size_t)B_ * H_ * 4, hipMemcpyDeviceToDevice, stream);

    // keys_proj: kp8 = fp8(encb @ Ua_w^T + Ua_b)
    gemm_mf<1><<<dim3((B_ * S_) / 64, H_ / 64), 256, 0, stream>>>(
        encb, Uaw_b, H_, H_, H_, nullptr, (unsigned char*)kp8, Ua_b);
    // Pemb (permuted): emb @ W_ih[:, :H](perm)^T + bsumP
    gemm_mf<0><<<dim3(V_ / 64, G4 / 64), 256, 0, stream>>>(
        emb_b, Wih1_b, H_, H_, G4, Pemb, nullptr, bsumP);

    // sequential decode: 4 launches per step (logits deferred)
    for (int t = 0; t < T_; ++t) {
        const unsigned short* hprev = (t == 0) ? hb0 : hall + (size_t)(t - 1) * B_ * H_;
        gemm_n32<2><<<dim3(2, 160), 256, 0, stream>>>(
            hprev, Wcat_b, H_, H_, 0, gates, nullptr, Wa_b,
            Pemb, toks + t * B_, qbuf, nullptr, 0);
        attn_e<<<dim3(B_, 8), 512, 0, stream>>>(kp8, qbuf, Va_w, encb8, es_g, pctx);
        attn_comb<<<dim3(B_, 2), 256, 0, stream>>>(es_g, pctx, ctxb, attn, t);
        gemm_n32<4><<<dim3(2, 128), 256, 0, stream>>>(
            ctxb, Wih2_b, H_, H_, 0, gates, hall + (size_t)t * B_ * H_, nullptr,
            nullptr, nullptr, cbuf, hid, t == T_ - 1);
    }

    // batched logits over all steps + log-softmax
    gemm_n32<0><<<dim3((T_ * B_) / 64, V_ / 32), 256, 0, stream>>>(
        hall, owb_b, H_, H_, V_, lgall, nullptr, out_b,
        nullptr, nullptr, nullptr, nullptr, 0);
    lsm_all<<<T_ * B_, 256, 0, stream>>>(lgall, lp);
}